// Round 1
// baseline (276.355 us; speedup 1.0000x reference)
//
#include <hip/hip_runtime.h>

// PETNNCell collapse (proven analytically):
//   T_t = R_t*gate(T_prev+Z_t) - 1 <= 0 always  =>  m == 1, T_t_out == 0
//   C_new = I_t + Z_c                          (C_prev dead)
//   C_scale == 0 => S_scaled == 0 => h = sigmoid(X @ W_h[:, :512]^T + b_h)
//   S_new = sigmoid((1 - Z_w)*S_prev + Z_w*h + X)
// Remaining work: fused 4-output GEMM (Zc, Zw: K=1024 over [X,S]; It, h: K=512 over X)
// with fully fused elementwise epilogue. bf16 MFMA internally (threshold 9.3e-2).

#define BROWS 16384
#define DDIM  512

typedef __bf16 bf16x8 __attribute__((ext_vector_type(8)));
typedef __bf16 bf16x4 __attribute__((ext_vector_type(4)));
typedef float  f32x4  __attribute__((ext_vector_type(4)));

__device__ __forceinline__ float sigf(float x) { return 1.0f / (1.0f + __expf(-x)); }

__device__ __forceinline__ bf16x4 cvt4(f32x4 v) {
    bf16x4 r;
    r[0] = (__bf16)v[0]; r[1] = (__bf16)v[1];
    r[2] = (__bf16)v[2]; r[3] = (__bf16)v[3];
    return r;
}

// Tile: BM=128 rows x BN=64 cols (per each of 4 outputs), BK=64.
// 256 threads = 4 waves in 2(M) x 2(N); wave tile 64x32 per output.
// LDS: sA[128][64] bf16 + 4x sB[64][64] bf16 = 48 KiB, XOR-swizzled
// (byte ^= (row&7)<<4  <=>  elem ^= (row&7)*8) to kill the 128B-stride conflict.
__global__ __launch_bounds__(256, 2)
void petnn_fused(const float* __restrict__ X,   const float* __restrict__ S,
                 const float* __restrict__ Wzc, const float* __restrict__ bzc,
                 const float* __restrict__ Wzw, const float* __restrict__ bzw,
                 const float* __restrict__ Wit, const float* __restrict__ bit_,
                 const float* __restrict__ Wh,  const float* __restrict__ bh,
                 float* __restrict__ out)
{
    __shared__ __align__(16) __bf16 sA[128 * 64];
    __shared__ __align__(16) __bf16 sB[4][64 * 64];

    const int tid  = threadIdx.x;
    const int bid  = blockIdx.x;
    const int nblk = bid & 7;    // 8 column blocks (512/64)
    const int mblk = bid >> 3;   // 128 row blocks
    const int lane = tid & 63;
    const int wid  = tid >> 6;
    const int wm   = wid >> 1;   // 0..1
    const int wn   = wid & 1;    // 0..1

    const int srow = tid >> 4;         // 0..15 (staging row within 16-row pass)
    const int skq  = (tid & 15) << 2;  // 0,4,...,60 (staging k offset, floats)

    const int arow0 = mblk * 128;
    const int nrow0 = nblk * 64;

    f32x4 aZc[4][2] = {}, aZw[4][2] = {}, aIt[4][2] = {}, aH[4][2] = {};
    f32x4 ra[8];    // A-tile prefetch regs (128x64 f32 / 256 thr = 8 float4)
    f32x4 rb[16];   // B-tiles prefetch regs (4 outputs x 64x64 / 256 thr)

    // ---- initial loads (kt = 0: X part, all four weight tiles) ----
    {
        #pragma unroll
        for (int p = 0; p < 8; ++p)
            ra[p] = *(const f32x4*)(X + (size_t)(arow0 + p * 16 + srow) * DDIM + skq);
        #pragma unroll
        for (int p = 0; p < 4; ++p) {
            const int n = nrow0 + p * 16 + srow;
            rb[p]      = *(const f32x4*)(Wzc + (size_t)n * 1024 + skq);
            rb[4 + p]  = *(const f32x4*)(Wzw + (size_t)n * 1024 + skq);
            rb[8 + p]  = *(const f32x4*)(Wit + (size_t)n * 512 + skq);
            rb[12 + p] = *(const f32x4*)(Wh  + (size_t)n * 1024 + skq);
        }
    }

    for (int kt = 0; kt < 16; ++kt) {
        const bool full = (kt < 8);   // X-part: all 4 outputs; S-part: Zc/Zw only
        if (kt) __syncthreads();      // previous tile's LDS reads done

        // ---- convert + write LDS (swizzled) ----
        #pragma unroll
        for (int p = 0; p < 8; ++p) {
            const int r = p * 16 + srow;
            *(bf16x4*)(sA + r * 64 + (skq ^ ((r & 7) * 8))) = cvt4(ra[p]);
        }
        #pragma unroll
        for (int p = 0; p < 4; ++p) {
            const int n  = p * 16 + srow;
            const int si = n * 64 + (skq ^ ((n & 7) * 8));
            *(bf16x4*)(sB[0] + si) = cvt4(rb[p]);
            *(bf16x4*)(sB[1] + si) = cvt4(rb[4 + p]);
        }
        if (full) {
            #pragma unroll
            for (int p = 0; p < 4; ++p) {
                const int n  = p * 16 + srow;
                const int si = n * 64 + (skq ^ ((n & 7) * 8));
                *(bf16x4*)(sB[2] + si) = cvt4(rb[8 + p]);
                *(bf16x4*)(sB[3] + si) = cvt4(rb[12 + p]);
            }
        }
        __syncthreads();

        // ---- issue next tile's global loads (in flight during MFMA) ----
        if (kt + 1 < 16) {
            const int ktn = kt + 1;
            const float* asrc = (ktn < 8) ? X : S;
            const int kga = (ktn & 7) * 64 + skq;
            #pragma unroll
            for (int p = 0; p < 8; ++p)
                ra[p] = *(const f32x4*)(asrc + (size_t)(arow0 + p * 16 + srow) * DDIM + kga);
            const int kgb = ktn * 64 + skq;    // concat-K index 0..1023
            #pragma unroll
            for (int p = 0; p < 4; ++p) {
                const int n = nrow0 + p * 16 + srow;
                rb[p]     = *(const f32x4*)(Wzc + (size_t)n * 1024 + kgb);
                rb[4 + p] = *(const f32x4*)(Wzw + (size_t)n * 1024 + kgb);
            }
            if (ktn < 8) {
                #pragma unroll
                for (int p = 0; p < 4; ++p) {
                    const int n = nrow0 + p * 16 + srow;
                    rb[8 + p]  = *(const f32x4*)(Wit + (size_t)n * 512 + kgb);
                    rb[12 + p] = *(const f32x4*)(Wh  + (size_t)n * 1024 + kgb);
                }
            }
        }

        // ---- MFMA phase ----
        #pragma unroll
        for (int kk = 0; kk < 2; ++kk) {
            const int kb = kk * 32 + (lane >> 4) * 8;
            bf16x8 af[4];
            #pragma unroll
            for (int mf = 0; mf < 4; ++mf) {
                const int r = wm * 64 + mf * 16 + (lane & 15);
                af[mf] = *(const bf16x8*)(sA + r * 64 + (kb ^ ((r & 7) * 8)));
            }
            #pragma unroll
            for (int nf = 0; nf < 2; ++nf) {
                const int n  = wn * 32 + nf * 16 + (lane & 15);
                const int si = n * 64 + (kb ^ ((n & 7) * 8));
                bf16x8 b0 = *(const bf16x8*)(sB[0] + si);
                bf16x8 b1 = *(const bf16x8*)(sB[1] + si);
                #pragma unroll
                for (int mf = 0; mf < 4; ++mf) {
                    aZc[mf][nf] = __builtin_amdgcn_mfma_f32_16x16x32_bf16(af[mf], b0, aZc[mf][nf], 0, 0, 0);
                    aZw[mf][nf] = __builtin_amdgcn_mfma_f32_16x16x32_bf16(af[mf], b1, aZw[mf][nf], 0, 0, 0);
                }
                if (full) {
                    bf16x8 b2 = *(const bf16x8*)(sB[2] + si);
                    bf16x8 b3 = *(const bf16x8*)(sB[3] + si);
                    #pragma unroll
                    for (int mf = 0; mf < 4; ++mf) {
                        aIt[mf][nf] = __builtin_amdgcn_mfma_f32_16x16x32_bf16(af[mf], b2, aIt[mf][nf], 0, 0, 0);
                        aH[mf][nf]  = __builtin_amdgcn_mfma_f32_16x16x32_bf16(af[mf], b3, aH[mf][nf], 0, 0, 0);
                    }
                }
            }
        }
    }

    // ---- fused epilogue ----
    // C/D frag layout (verified, m89/m91): col = lane&15, row = (lane>>4)*4 + reg
    const int colb = nrow0 + wn * 32;
    const int rowb = arow0 + wm * 64;
    #pragma unroll
    for (int nf = 0; nf < 2; ++nf) {
        const int col = colb + nf * 16 + (lane & 15);
        const float vzc = bzc[col], vzw = bzw[col], vit = bit_[col], vh = bh[col];
        #pragma unroll
        for (int mf = 0; mf < 4; ++mf) {
            #pragma unroll
            for (int j = 0; j < 4; ++j) {
                const int row = rowb + mf * 16 + ((lane >> 4) << 2) + j;
                const size_t off = (size_t)row * DDIM + col;
                const float zw = sigf(aZw[mf][nf][j] + vzw);
                const float hh = sigf(aH[mf][nf][j] + vh);
                const float sn = sigf((1.0f - zw) * S[off] + zw * hh + X[off]);
                out[off] = sn;                                              // S_new
                out[(size_t)BROWS * DDIM + off] =
                    (aZc[mf][nf][j] + vzc) + (aIt[mf][nf][j] + vit);        // C_new
            }
        }
    }
}

__global__ void petnn_zeroT(float* __restrict__ t) {
    t[blockIdx.x * 256 + threadIdx.x] = 0.0f;   // T_t == 0 exactly
}

extern "C" void kernel_launch(void* const* d_in, const int* in_sizes, int n_in,
                              void* d_out, int out_size, void* d_ws, size_t ws_size,
                              hipStream_t stream) {
    (void)in_sizes; (void)n_in; (void)d_ws; (void)ws_size; (void)out_size;
    const float* X    = (const float*)d_in[0];
    const float* S    = (const float*)d_in[1];
    // d_in[2] C_prev, d_in[3] T_prev, d_in[4/5] W_Zt/b_Zt, d_in[12/13] W_Rt/b_Rt: dead
    const float* Wzc  = (const float*)d_in[6];
    const float* bzc  = (const float*)d_in[7];
    const float* Wzw  = (const float*)d_in[8];
    const float* bzw  = (const float*)d_in[9];
    const float* Wit  = (const float*)d_in[10];
    const float* bit_ = (const float*)d_in[11];
    const float* Wh   = (const float*)d_in[14];
    const float* bh   = (const float*)d_in[15];
    float* out = (float*)d_out;

    petnn_fused<<<dim3(128 * 8), dim3(256), 0, stream>>>(
        X, S, Wzc, bzc, Wzw, bzw, Wit, bit_, Wh, bh, out);
    petnn_zeroT<<<dim3(64), dim3(256), 0, stream>>>(out + 2 * (size_t)BROWS * DDIM);
}

// Round 2
// 119.788 us; speedup vs baseline: 2.3070x; 2.3070x over previous
//
#include <hip/hip_runtime.h>

// PETNNCell collapse (proven analytically):
//   T_t = R_t*gate(T_prev+Z_t) - 1 <= 0 always  =>  m == 1, T_t_out == 0
//   C_new = I_t + Z_c                          (C_prev dead)
//   C_scale == 0 => S_scaled == 0 => h = sigmoid(X @ W_h[:, :512]^T + b_h)
//   S_new = sigmoid((1 - Z_w)*S_prev + Z_w*h + X)
// Fused 4-output GEMM (Zc, Zw: K=1024 over [X,S]; It, h: K=512 over X).
//
// R2: (a) XCD-chunked swizzle, nblk-minor: the 8 column-siblings of each
//     mblk run concurrently on ONE XCD -> A row-panel fetched once per XCD
//     (was 8x = 512 MB of the measured 476 MB FETCH).
//     (b) 512 threads / 8 waves per block: 16 waves/CU (was 8).

#define BROWS 16384
#define DDIM  512

typedef __bf16 bf16x8 __attribute__((ext_vector_type(8)));
typedef __bf16 bf16x4 __attribute__((ext_vector_type(4)));
typedef float  f32x4  __attribute__((ext_vector_type(4)));

__device__ __forceinline__ float sigf(float x) { return 1.0f / (1.0f + __expf(-x)); }

__device__ __forceinline__ bf16x4 cvt4(f32x4 v) {
    bf16x4 r;
    r[0] = (__bf16)v[0]; r[1] = (__bf16)v[1];
    r[2] = (__bf16)v[2]; r[3] = (__bf16)v[3];
    return r;
}

// Tile: BM=128 x BN=64 (per each of 4 outputs), BK=64. 512 threads = 8 waves
// in 2(M) x 4(N); wave tile 64x16 per output. LDS 48 KiB, XOR-swizzled
// (elem ^= (row&7)*8) to kill the 128B-stride bank conflict (measured 0).
__global__ __launch_bounds__(512, 2)
void petnn_fused(const float* __restrict__ X,   const float* __restrict__ S,
                 const float* __restrict__ Wzc, const float* __restrict__ bzc,
                 const float* __restrict__ Wzw, const float* __restrict__ bzw,
                 const float* __restrict__ Wit, const float* __restrict__ bit_,
                 const float* __restrict__ Wh,  const float* __restrict__ bh,
                 float* __restrict__ out)
{
    __shared__ __align__(16) __bf16 sA[128 * 64];
    __shared__ __align__(16) __bf16 sB[4][64 * 64];

    const int tid = threadIdx.x;
    const int bid = blockIdx.x;
    // XCD-chunked swizzle (bijective, nwg=1024 % 8 == 0). HW: XCD = bid & 7.
    // XCD k owns orig range [k*128, (k+1)*128) = 16 mblks x all 8 nblks,
    // walked nblk-minor -> 8 siblings of an mblk co-resident on one XCD.
    const int orig = (bid & 7) * 128 + (bid >> 3);
    const int mblk = orig >> 3;
    const int nblk = orig & 7;

    const int lane = tid & 63;
    const int wid  = tid >> 6;
    const int wm   = wid >> 2;   // 0..1 (M half)
    const int wn   = wid & 3;    // 0..3 (16-col slice)

    const int srow = tid >> 4;         // 0..31 staging row
    const int skq  = (tid & 15) << 2;  // staging k offset (floats)

    const int arow0 = mblk * 128;
    const int nrow0 = nblk * 64;

    f32x4 aZc[4] = {}, aZw[4] = {}, aIt[4] = {}, aH[4] = {};
    f32x4 ra[4];   // A prefetch: 128x64 f32 / 512 thr = 4 float4
    f32x4 rb[8];   // B prefetch: 4 outputs x 64x64 / 512 thr = 8 float4

    // ---- initial loads (kt = 0) ----
    #pragma unroll
    for (int p = 0; p < 4; ++p)
        ra[p] = *(const f32x4*)(X + (size_t)(arow0 + p * 32 + srow) * DDIM + skq);
    #pragma unroll
    for (int p = 0; p < 2; ++p) {
        const int n = nrow0 + p * 32 + srow;
        rb[p]     = *(const f32x4*)(Wzc + (size_t)n * 1024 + skq);
        rb[2 + p] = *(const f32x4*)(Wzw + (size_t)n * 1024 + skq);
        rb[4 + p] = *(const f32x4*)(Wit + (size_t)n * 512 + skq);
        rb[6 + p] = *(const f32x4*)(Wh  + (size_t)n * 1024 + skq);
    }

    for (int kt = 0; kt < 16; ++kt) {
        const bool full = (kt < 8);   // X-part: 4 outputs; S-part: Zc/Zw only
        if (kt) __syncthreads();      // prev tile's LDS reads done

        // ---- convert + write LDS (swizzled) ----
        #pragma unroll
        for (int p = 0; p < 4; ++p) {
            const int r = p * 32 + srow;
            *(bf16x4*)(sA + r * 64 + (skq ^ ((r & 7) * 8))) = cvt4(ra[p]);
        }
        #pragma unroll
        for (int p = 0; p < 2; ++p) {
            const int n  = p * 32 + srow;
            const int si = n * 64 + (skq ^ ((n & 7) * 8));
            *(bf16x4*)(sB[0] + si) = cvt4(rb[p]);
            *(bf16x4*)(sB[1] + si) = cvt4(rb[2 + p]);
            if (full) {
                *(bf16x4*)(sB[2] + si) = cvt4(rb[4 + p]);
                *(bf16x4*)(sB[3] + si) = cvt4(rb[6 + p]);
            }
        }
        __syncthreads();

        // ---- issue next tile's global loads (in flight during MFMA) ----
        if (kt + 1 < 16) {
            const int ktn = kt + 1;
            const float* asrc = (ktn < 8) ? X : S;
            const int kga = (ktn & 7) * 64 + skq;
            #pragma unroll
            for (int p = 0; p < 4; ++p)
                ra[p] = *(const f32x4*)(asrc + (size_t)(arow0 + p * 32 + srow) * DDIM + kga);
            const int kgb = ktn * 64 + skq;   // concat-K 0..1023
            #pragma unroll
            for (int p = 0; p < 2; ++p) {
                const int n = nrow0 + p * 32 + srow;
                rb[p]     = *(const f32x4*)(Wzc + (size_t)n * 1024 + kgb);
                rb[2 + p] = *(const f32x4*)(Wzw + (size_t)n * 1024 + kgb);
                if (ktn < 8) {
                    rb[4 + p] = *(const f32x4*)(Wit + (size_t)n * 512 + kgb);
                    rb[6 + p] = *(const f32x4*)(Wh  + (size_t)n * 1024 + kgb);
                }
            }
        }

        // ---- MFMA phase ----
        #pragma unroll
        for (int kk = 0; kk < 2; ++kk) {
            const int kb = kk * 32 + (lane >> 4) * 8;
            bf16x8 af[4];
            #pragma unroll
            for (int mf = 0; mf < 4; ++mf) {
                const int r = wm * 64 + mf * 16 + (lane & 15);
                af[mf] = *(const bf16x8*)(sA + r * 64 + (kb ^ ((r & 7) * 8)));
            }
            const int n  = wn * 16 + (lane & 15);
            const int si = n * 64 + (kb ^ ((n & 7) * 8));
            bf16x8 b0 = *(const bf16x8*)(sB[0] + si);
            bf16x8 b1 = *(const bf16x8*)(sB[1] + si);
            #pragma unroll
            for (int mf = 0; mf < 4; ++mf) {
                aZc[mf] = __builtin_amdgcn_mfma_f32_16x16x32_bf16(af[mf], b0, aZc[mf], 0, 0, 0);
                aZw[mf] = __builtin_amdgcn_mfma_f32_16x16x32_bf16(af[mf], b1, aZw[mf], 0, 0, 0);
            }
            if (full) {
                bf16x8 b2 = *(const bf16x8*)(sB[2] + si);
                bf16x8 b3 = *(const bf16x8*)(sB[3] + si);
                #pragma unroll
                for (int mf = 0; mf < 4; ++mf) {
                    aIt[mf] = __builtin_amdgcn_mfma_f32_16x16x32_bf16(af[mf], b2, aIt[mf], 0, 0, 0);
                    aH[mf]  = __builtin_amdgcn_mfma_f32_16x16x32_bf16(af[mf], b3, aH[mf], 0, 0, 0);
                }
            }
        }
    }

    // ---- fused epilogue ----
    // C/D frag layout (m89/m91): col = lane&15, row = (lane>>4)*4 + reg
    const int col = nrow0 + wn * 16 + (lane & 15);
    const int rowb = arow0 + wm * 64;
    const float vzc = bzc[col], vzw = bzw[col], vit = bit_[col], vh = bh[col];
    #pragma unroll
    for (int mf = 0; mf < 4; ++mf) {
        #pragma unroll
        for (int j = 0; j < 4; ++j) {
            const int row = rowb + mf * 16 + ((lane >> 4) << 2) + j;
            const size_t off = (size_t)row * DDIM + col;
            const float zw = sigf(aZw[mf][j] + vzw);
            const float hh = sigf(aH[mf][j] + vh);
            const float sn = sigf((1.0f - zw) * S[off] + zw * hh + X[off]);
            out[off] = sn;                                      // S_new
            out[(size_t)BROWS * DDIM + off] =
                (aZc[mf][j] + vzc) + (aIt[mf][j] + vit);        // C_new
        }
    }
}

__global__ void petnn_zeroT(float* __restrict__ t) {
    t[blockIdx.x * 256 + threadIdx.x] = 0.0f;   // T_t == 0 exactly
}

extern "C" void kernel_launch(void* const* d_in, const int* in_sizes, int n_in,
                              void* d_out, int out_size, void* d_ws, size_t ws_size,
                              hipStream_t stream) {
    (void)in_sizes; (void)n_in; (void)d_ws; (void)ws_size; (void)out_size;
    const float* X    = (const float*)d_in[0];
    const float* S    = (const float*)d_in[1];
    const float* Wzc  = (const float*)d_in[6];
    const float* bzc  = (const float*)d_in[7];
    const float* Wzw  = (const float*)d_in[8];
    const float* bzw  = (const float*)d_in[9];
    const float* Wit  = (const float*)d_in[10];
    const float* bit_ = (const float*)d_in[11];
    const float* Wh   = (const float*)d_in[14];
    const float* bh   = (const float*)d_in[15];
    float* out = (float*)d_out;

    petnn_fused<<<dim3(128 * 8), dim3(512), 0, stream>>>(
        X, S, Wzc, bzc, Wzw, bzw, Wit, bit_, Wh, bh, out);
    petnn_zeroT<<<dim3(64), dim3(256), 0, stream>>>(out + 2 * (size_t)BROWS * DDIM);
}